// Round 1
// baseline (21410.200 us; speedup 1.0000x reference)
//
#include <hip/hip_runtime.h>
#include <hip/hip_cooperative_groups.h>

namespace cg = cooperative_groups;

static constexpr int   B_  = 64;
static constexpr int   T_  = 256;
static constexpr int   D_  = 512;
static constexpr int   N_  = 1024;
static constexpr float ALPHA_ = 0.9f;
static constexpr float BETA_  = 0.85f;
static constexpr float THR_   = 0.1f;

// ================= Kernel 1: H = X @ W (fp32, 128x128 tiles) =================
// X: [B*T, D] row-major (row r = b*T + t), W: [D, N], H: [B*T, N]
__global__ __launch_bounds__(256) void dsrnn_hgemm(const float* __restrict__ X,
                                                   const float* __restrict__ W,
                                                   float* __restrict__ H) {
  __shared__ float As[16][128];
  __shared__ float Bs[16][128];
  const int tid = threadIdx.x;
  const int nb  = blockIdx.x & 7;   // 8 col tiles of 128
  const int mb  = blockIdx.x >> 3;  // 128 row tiles of 128
  const int r0  = mb << 7;
  const int n0  = nb << 7;

  float acc[8][8];
#pragma unroll
  for (int i = 0; i < 8; ++i)
#pragma unroll
    for (int j = 0; j < 8; ++j) acc[i][j] = 0.f;

  for (int k0 = 0; k0 < D_; k0 += 16) {
    // A tile 128x16 -> As[k][row] (transposed store)
#pragma unroll
    for (int i = 0; i < 2; ++i) {
      const int f   = tid * 2 + i;      // 0..511
      const int row = f >> 2;
      const int kq  = (f & 3) << 2;
      const float4 v =
          *reinterpret_cast<const float4*>(&X[(size_t)(r0 + row) * D_ + k0 + kq]);
      As[kq + 0][row] = v.x;
      As[kq + 1][row] = v.y;
      As[kq + 2][row] = v.z;
      As[kq + 3][row] = v.w;
    }
    // B tile 16x128 -> Bs[k][col]
#pragma unroll
    for (int i = 0; i < 2; ++i) {
      const int f  = tid * 2 + i;
      const int kr = f >> 5;
      const int c  = (f & 31) << 2;
      *reinterpret_cast<float4*>(&Bs[kr][c]) =
          *reinterpret_cast<const float4*>(&W[(size_t)(k0 + kr) * N_ + n0 + c]);
    }
    __syncthreads();
    const int ty = tid >> 4, tx = tid & 15;
#pragma unroll
    for (int kk = 0; kk < 16; ++kk) {
      float a[8], b[8];
      *reinterpret_cast<float4*>(&a[0]) = *reinterpret_cast<const float4*>(&As[kk][ty * 8]);
      *reinterpret_cast<float4*>(&a[4]) = *reinterpret_cast<const float4*>(&As[kk][ty * 8 + 4]);
      *reinterpret_cast<float4*>(&b[0]) = *reinterpret_cast<const float4*>(&Bs[kk][tx * 8]);
      *reinterpret_cast<float4*>(&b[4]) = *reinterpret_cast<const float4*>(&Bs[kk][tx * 8 + 4]);
#pragma unroll
      for (int i = 0; i < 8; ++i)
#pragma unroll
        for (int j = 0; j < 8; ++j) acc[i][j] = fmaf(a[i], b[j], acc[i][j]);
    }
    __syncthreads();
  }
  const int ty = tid >> 4, tx = tid & 15;
#pragma unroll
  for (int i = 0; i < 8; ++i) {
    const size_t r = (size_t)(r0 + ty * 8 + i);
#pragma unroll
    for (int j = 0; j < 8; j += 4)
      *reinterpret_cast<float4*>(&H[r * N_ + n0 + tx * 8 + j]) =
          *reinterpret_cast<const float4*>(&acc[i][j]);
  }
}

// ================= Kernel 2: fused sequential SNN loop (cooperative) ==========
// Grid: 256 WGs x 256 threads. WG w: m-group (w&15)*64, b-group (w>>4)*4.
// Wave (threadIdx>>6) = local b; lane = local m. State (mem, syn) in registers.
// Spikes communicated as double-buffered bitmasks in d_ws: masks[2][B][16] u64.
__global__ __launch_bounds__(256) void dsrnn_step(
    const float* __restrict__ Rw,  // [N, N]
    float* __restrict__ spk_rec,   // [B,T,N]
    float* __restrict__ mem_rec,   // [B,T,N]
    float* __restrict__ syn_rec,   // [B,T,N]; pre-filled with H, overwritten with syn
    float* __restrict__ mem_fin,   // [B,N]
    float* __restrict__ syn_fin,   // [B,N]
    float* __restrict__ spk_fin,   // [B,N]
    unsigned long long* masks)     // [2][B][16]
{
  cg::grid_group grid = cg::this_grid();
  const int mgrp = blockIdx.x & 15;
  const int bgrp = blockIdx.x >> 4;
  const int wave = threadIdx.x >> 6;
  const int lane = threadIdx.x & 63;
  const int b = bgrp * 4 + wave;
  const int m = mgrp * 64 + lane;

  float mem = 0.f, syn = 0.f, spike = 0.f;
  const float* Rcol = Rw + m;  // R[n][m] = Rcol[n * N_]

  for (int t = 0; t < T_; ++t) {
    float acc = 0.f;
    if (t > 0) {
      const unsigned long long* mrow = masks + (size_t)(t & 1) * (B_ * 16) + b * 16;
#pragma unroll 4
      for (int w = 0; w < 16; ++w) {
        unsigned long long bits = mrow[w];  // wave-uniform (same b across wave)
        const int nbase = w << 6;
        while (bits) {
          const int j = __builtin_ctzll(bits);
          bits &= bits - 1;
          acc += Rcol[(size_t)(nbase + j) << 10];
        }
      }
    }
    const size_t idx = ((size_t)b * T_ + t) * N_ + m;
    const float h = syn_rec[idx];  // precomputed input projection lives here
    syn = ALPHA_ * syn + h + acc;
    mem = BETA_ * mem + syn;
    const float mthr = mem - THR_;
    const bool sp = mthr > 0.f;
    spike = sp ? 1.f : 0.f;
    mem = sp ? 0.f : mem;
    spk_rec[idx] = spike;
    mem_rec[idx] = mem;
    syn_rec[idx] = syn;  // overwrites the H slot (last use was this step)
    const unsigned long long ball = __ballot(sp);
    if (lane == 0)
      masks[(size_t)((t + 1) & 1) * (B_ * 16) + b * 16 + mgrp] = ball;
    grid.sync();
  }
  const int fi = b * N_ + m;
  mem_fin[fi] = mem;
  syn_fin[fi] = syn;
  spk_fin[fi] = spike;
}

// ============================== launcher =====================================
extern "C" void kernel_launch(void* const* d_in, const int* in_sizes, int n_in,
                              void* d_out, int out_size, void* d_ws, size_t ws_size,
                              hipStream_t stream) {
  const float* X  = (const float*)d_in[0];  // [B,T,D]
  const float* W  = (const float*)d_in[1];  // [D,N]
  const float* Rw = (const float*)d_in[2];  // [N,N]

  float* out = (float*)d_out;
  const size_t BTN = (size_t)B_ * T_ * N_;
  const size_t BN  = (size_t)B_ * N_;
  float* spk_rec = out;
  float* mem_fin = out + BTN;
  float* syn_fin = mem_fin + BN;
  float* spk_fin = syn_fin + BN;
  float* mem_rec = spk_fin + BN;
  float* syn_rec = mem_rec + BTN;  // doubles as the H buffer

  unsigned long long* masks = (unsigned long long*)d_ws;
  // zero the double-buffered spike masks (t=0 reads buffer 0; harness doesn't re-poison)
  hipMemsetAsync(d_ws, 0, (size_t)2 * B_ * 16 * sizeof(unsigned long long), stream);

  // Phase 1: H = X @ W into the syn_rec region
  dsrnn_hgemm<<<dim3(1024), dim3(256), 0, stream>>>(X, W, syn_rec);

  // Phase 2: fused 256-step recurrence (cooperative, grid-wide sync per step)
  void* args[] = {(void*)&Rw,     (void*)&spk_rec, (void*)&mem_rec,
                  (void*)&syn_rec, (void*)&mem_fin, (void*)&syn_fin,
                  (void*)&spk_fin, (void*)&masks};
  hipLaunchCooperativeKernel((void*)dsrnn_step, dim3(256), dim3(256), args, 0,
                             stream);
}

// Round 3
// 9316.207 us; speedup vs baseline: 2.2982x; 2.2982x over previous
//
#include <hip/hip_runtime.h>
#include <hip/hip_cooperative_groups.h>

namespace cg = cooperative_groups;

static constexpr int   B_  = 64;
static constexpr int   T_  = 256;
static constexpr int   D_  = 512;
static constexpr int   N_  = 1024;
static constexpr float ALPHA_ = 0.9f;
static constexpr float BETA_  = 0.85f;
static constexpr float THR_   = 0.1f;

// ================= Kernel 1: H = X @ W (fp32, 128x128 tiles) =================
__global__ __launch_bounds__(256) void dsrnn_hgemm(const float* __restrict__ X,
                                                   const float* __restrict__ W,
                                                   float* __restrict__ H) {
  __shared__ float As[16][128];
  __shared__ float Bs[16][128];
  const int tid = threadIdx.x;
  const int nb  = blockIdx.x & 7;
  const int mb  = blockIdx.x >> 3;
  const int r0  = mb << 7;
  const int n0  = nb << 7;

  float acc[8][8];
#pragma unroll
  for (int i = 0; i < 8; ++i)
#pragma unroll
    for (int j = 0; j < 8; ++j) acc[i][j] = 0.f;

  for (int k0 = 0; k0 < D_; k0 += 16) {
#pragma unroll
    for (int i = 0; i < 2; ++i) {
      const int f   = tid * 2 + i;
      const int row = f >> 2;
      const int kq  = (f & 3) << 2;
      const float4 v =
          *reinterpret_cast<const float4*>(&X[(size_t)(r0 + row) * D_ + k0 + kq]);
      As[kq + 0][row] = v.x;
      As[kq + 1][row] = v.y;
      As[kq + 2][row] = v.z;
      As[kq + 3][row] = v.w;
    }
#pragma unroll
    for (int i = 0; i < 2; ++i) {
      const int f  = tid * 2 + i;
      const int kr = f >> 5;
      const int c  = (f & 31) << 2;
      *reinterpret_cast<float4*>(&Bs[kr][c]) =
          *reinterpret_cast<const float4*>(&W[(size_t)(k0 + kr) * N_ + n0 + c]);
    }
    __syncthreads();
    const int ty = tid >> 4, tx = tid & 15;
#pragma unroll
    for (int kk = 0; kk < 16; ++kk) {
      float a[8], b[8];
      *reinterpret_cast<float4*>(&a[0]) = *reinterpret_cast<const float4*>(&As[kk][ty * 8]);
      *reinterpret_cast<float4*>(&a[4]) = *reinterpret_cast<const float4*>(&As[kk][ty * 8 + 4]);
      *reinterpret_cast<float4*>(&b[0]) = *reinterpret_cast<const float4*>(&Bs[kk][tx * 8]);
      *reinterpret_cast<float4*>(&b[4]) = *reinterpret_cast<const float4*>(&Bs[kk][tx * 8 + 4]);
#pragma unroll
      for (int i = 0; i < 8; ++i)
#pragma unroll
        for (int j = 0; j < 8; ++j) acc[i][j] = fmaf(a[i], b[j], acc[i][j]);
    }
    __syncthreads();
  }
  const int ty = tid >> 4, tx = tid & 15;
#pragma unroll
  for (int i = 0; i < 8; ++i) {
    const size_t r = (size_t)(r0 + ty * 8 + i);
#pragma unroll
    for (int j = 0; j < 8; j += 4)
      *reinterpret_cast<float4*>(&H[r * N_ + n0 + tx * 8 + j]) =
          *reinterpret_cast<const float4*>(&acc[i][j]);
  }
}

// ========== Kernel 2: persistent register-resident recurrence (8-way K) ======
// 256 WGs x 256 threads. WG = (bgrp 0..7 = bid>>5, mgrp 0..31 = bid&31).
// Lane l of wave w: o = l>>3 (K-slice AND owned-b), mi = l&7.
//   owned output: b = bgrp*8 + o,  m = mgrp*32 + w*8 + mi
//   register slice: r[i] = R[o*128 + i][m], i = 0..127   (128 VGPRs)
// Spike masks: u64 masks[2][64 b][16 words]; per-b byte j covers n=[j*8,j*8+8).
__global__ __launch_bounds__(256, 2) void dsrnn_step3(
    const float* __restrict__ Rw,
    float* __restrict__ spk_rec,
    float* __restrict__ mem_rec,
    float* __restrict__ syn_rec,   // pre-filled with H, overwritten with syn
    float* __restrict__ mem_fin,
    float* __restrict__ syn_fin,
    float* __restrict__ spk_fin,
    unsigned long long* masks)
{
  cg::grid_group grid = cg::this_grid();
  const int mgrp = blockIdx.x & 31;
  const int bgrp = blockIdx.x >> 5;
  const int wave = threadIdx.x >> 6;
  const int lane = threadIdx.x & 63;
  const int o  = lane >> 3;
  const int mi = lane & 7;
  const int m = (mgrp << 5) + (wave << 3) + mi;
  const int b = (bgrp << 3) + o;

  // one-time preload of the R slice into registers
  float r[128];
  {
    const float* p = Rw + ((size_t)(o << 7)) * N_ + m;
#pragma unroll
    for (int i = 0; i < 128; ++i) r[i] = p[(size_t)i * N_];
  }

  __shared__ unsigned long long smaskL[128];  // [8 b][16 words]
  float mem = 0.f, syn = 0.f, spike = 0.f;
  const bool l0 = (o & 1) != 0;
  const bool l1 = ((o >> 1) & 1) != 0;
  const bool l2 = ((o >> 2) & 1) != 0;

  for (int t = 0; t < T_; ++t) {
    const size_t idx = ((size_t)b * T_ + t) * N_ + m;
    const float h = syn_rec[idx];  // issue early

    // stage this bgrp's 8 spike-mask rows (128 u64) into LDS
    const unsigned long long* mc = masks + (size_t)(t & 1) * (64 * 16);
    if (threadIdx.x < 128)
      smaskL[threadIdx.x] = mc[(size_t)bgrp * 128 + threadIdx.x];
    __syncthreads();

    unsigned long long bb[8][2];
#pragma unroll
    for (int j = 0; j < 8; ++j) {
      bb[j][0] = smaskL[j * 16 + (o << 1) + 0];
      bb[j][1] = smaskL[j * 16 + (o << 1) + 1];
    }

    // dense register GEMV: partials for the WG's 8 b's over this o's n-slice
    float pj[8];
#pragma unroll
    for (int j = 0; j < 8; ++j) pj[j] = 0.f;
#pragma unroll
    for (int w = 0; w < 2; ++w) {
#pragma unroll
      for (int i = 0; i < 64; ++i) {
        const float rv = r[(w << 6) + i];
#pragma unroll
        for (int j = 0; j < 8; ++j)
          pj[j] += rv * (float)(unsigned int)((bb[j][w] >> i) & 1ull);
      }
    }

    // 3-stage reduce-scatter across o (lanes l, l^8, l^16, l^32): lane o ends
    // with the full sum for j == o. Explicit ternaries keep arrays in regs.
    float q0, q1, q2, q3;
    {
      float s, k;
      k = l0 ? pj[1] : pj[0]; s = l0 ? pj[0] : pj[1]; q0 = k + __shfl_xor(s, 8);
      k = l0 ? pj[3] : pj[2]; s = l0 ? pj[2] : pj[3]; q1 = k + __shfl_xor(s, 8);
      k = l0 ? pj[5] : pj[4]; s = l0 ? pj[4] : pj[5]; q2 = k + __shfl_xor(s, 8);
      k = l0 ? pj[7] : pj[6]; s = l0 ? pj[6] : pj[7]; q3 = k + __shfl_xor(s, 8);
    }
    float u0, u1;
    {
      float s, k;
      k = l1 ? q1 : q0; s = l1 ? q0 : q1; u0 = k + __shfl_xor(s, 16);
      k = l1 ? q3 : q2; s = l1 ? q2 : q3; u1 = k + __shfl_xor(s, 16);
    }
    float rec;
    {
      const float s = l2 ? u0 : u1;
      const float k = l2 ? u1 : u0;
      rec = k + __shfl_xor(s, 32);
    }

    // state update for owned (b, m)
    syn = ALPHA_ * syn + h + rec;
    mem = BETA_ * mem + syn;
    const float mthr = mem - THR_;
    const bool sp = mthr > 0.f;
    spike = sp ? 1.f : 0.f;
    mem = sp ? 0.f : mem;
    spk_rec[idx] = spike;
    mem_rec[idx] = mem;
    syn_rec[idx] = syn;

    // publish spikes: ballot bits [o*8, o*8+8) = (b = bgrp*8+o, m-run of 8)
    const unsigned long long ball = __ballot(sp);
    if (mi == 0) {
      unsigned char* mn =
          (unsigned char*)(masks + (size_t)((t + 1) & 1) * (64 * 16));
      mn[(size_t)b * 128 + (mgrp << 2) + wave] = (unsigned char)(ball >> (o << 3));
    }
    grid.sync();
  }

  const int fi = b * N_ + m;
  mem_fin[fi] = mem;
  syn_fin[fi] = syn;
  spk_fin[fi] = spike;
}

// ============================== launcher =====================================
extern "C" void kernel_launch(void* const* d_in, const int* in_sizes, int n_in,
                              void* d_out, int out_size, void* d_ws, size_t ws_size,
                              hipStream_t stream) {
  const float* X  = (const float*)d_in[0];
  const float* W  = (const float*)d_in[1];
  const float* Rw = (const float*)d_in[2];

  float* out = (float*)d_out;
  const size_t BTN = (size_t)B_ * T_ * N_;
  const size_t BN  = (size_t)B_ * N_;
  float* spk_rec = out;
  float* mem_fin = out + BTN;
  float* syn_fin = mem_fin + BN;
  float* spk_fin = syn_fin + BN;
  float* mem_rec = spk_fin + BN;
  float* syn_rec = mem_rec + BTN;  // doubles as the H buffer

  unsigned long long* masks = (unsigned long long*)d_ws;
  hipMemsetAsync(d_ws, 0, (size_t)2 * 64 * 16 * sizeof(unsigned long long), stream);

  dsrnn_hgemm<<<dim3(1024), dim3(256), 0, stream>>>(X, W, syn_rec);

  void* args[] = {(void*)&Rw,      (void*)&spk_rec, (void*)&mem_rec,
                  (void*)&syn_rec, (void*)&mem_fin, (void*)&syn_fin,
                  (void*)&spk_fin, (void*)&masks};
  hipLaunchCooperativeKernel((void*)dsrnn_step3, dim3(256), dim3(256), args, 0,
                             stream);
}

// Round 4
// 5606.771 us; speedup vs baseline: 3.8186x; 1.6616x over previous
//
#include <hip/hip_runtime.h>

static constexpr int   B_  = 64;
static constexpr int   T_  = 256;
static constexpr int   D_  = 512;
static constexpr int   N_  = 1024;
static constexpr float ALPHA_ = 0.9f;
static constexpr float BETA_  = 0.85f;
static constexpr float THR_   = 0.1f;

// ================= Kernel 1: H = X @ W (fp32, 128x128 tiles) =================
__global__ __launch_bounds__(256) void dsrnn_hgemm(const float* __restrict__ X,
                                                   const float* __restrict__ W,
                                                   float* __restrict__ H) {
  __shared__ float As[16][128];
  __shared__ float Bs[16][128];
  const int tid = threadIdx.x;
  const int nb  = blockIdx.x & 7;
  const int mb  = blockIdx.x >> 3;
  const int r0  = mb << 7;
  const int n0  = nb << 7;

  float acc[8][8];
#pragma unroll
  for (int i = 0; i < 8; ++i)
#pragma unroll
    for (int j = 0; j < 8; ++j) acc[i][j] = 0.f;

  for (int k0 = 0; k0 < D_; k0 += 16) {
#pragma unroll
    for (int i = 0; i < 2; ++i) {
      const int f   = tid * 2 + i;
      const int row = f >> 2;
      const int kq  = (f & 3) << 2;
      const float4 v =
          *reinterpret_cast<const float4*>(&X[(size_t)(r0 + row) * D_ + k0 + kq]);
      As[kq + 0][row] = v.x;
      As[kq + 1][row] = v.y;
      As[kq + 2][row] = v.z;
      As[kq + 3][row] = v.w;
    }
#pragma unroll
    for (int i = 0; i < 2; ++i) {
      const int f  = tid * 2 + i;
      const int kr = f >> 5;
      const int c  = (f & 31) << 2;
      *reinterpret_cast<float4*>(&Bs[kr][c]) =
          *reinterpret_cast<const float4*>(&W[(size_t)(k0 + kr) * N_ + n0 + c]);
    }
    __syncthreads();
    const int ty = tid >> 4, tx = tid & 15;
#pragma unroll
    for (int kk = 0; kk < 16; ++kk) {
      float a[8], b[8];
      *reinterpret_cast<float4*>(&a[0]) = *reinterpret_cast<const float4*>(&As[kk][ty * 8]);
      *reinterpret_cast<float4*>(&a[4]) = *reinterpret_cast<const float4*>(&As[kk][ty * 8 + 4]);
      *reinterpret_cast<float4*>(&b[0]) = *reinterpret_cast<const float4*>(&Bs[kk][tx * 8]);
      *reinterpret_cast<float4*>(&b[4]) = *reinterpret_cast<const float4*>(&Bs[kk][tx * 8 + 4]);
#pragma unroll
      for (int i = 0; i < 8; ++i)
#pragma unroll
        for (int j = 0; j < 8; ++j) acc[i][j] = fmaf(a[i], b[j], acc[i][j]);
    }
    __syncthreads();
  }
  const int ty = tid >> 4, tx = tid & 15;
#pragma unroll
  for (int i = 0; i < 8; ++i) {
    const size_t r = (size_t)(r0 + ty * 8 + i);
#pragma unroll
    for (int j = 0; j < 8; j += 4)
      *reinterpret_cast<float4*>(&H[r * N_ + n0 + tx * 8 + j]) =
          *reinterpret_cast<const float4*>(&acc[i][j]);
  }
}

// ====== Kernel 2: persistent recurrence, R in LDS, tagged-dataflow sync ======
// 256 WGs x 256 threads, coop-launched (co-residency) but NO grid.sync.
// WG = (bgrp = bid>>5 in 0..7, mgrp = bid&31 in 0..31): owns 8 b's x 32 m's.
// Thread: wave w = tid>>6, lane l = tid&63, o = l>>3 (K-slice & owned-b),
//         mi = l&7.  owned: b = bgrp*8+o, m = mgrp*32 + w*8 + mi.
// LDS Rs (dynamic, 128 KB): word idx = n*32 + ((mm + 4*(n>>7)) & 31)  (2-way max).
// Spike exchange: u64 masks[2][64 b][32 chunks], word = (tag << 32) | bits32,
//   tag = step+1 of the producing step; slot = tag & 1. Acquire/release, agent.
__global__ __launch_bounds__(256, 1) void dsrnn_step4(
    const float* __restrict__ Rw,
    float* __restrict__ spk_rec,
    float* __restrict__ mem_rec,
    float* __restrict__ syn_rec,   // pre-filled with H, overwritten with syn
    float* __restrict__ mem_fin,
    float* __restrict__ syn_fin,
    float* __restrict__ spk_fin,
    unsigned long long* masks)
{
  extern __shared__ float Rs[];               // [1024][32] swizzled
  __shared__ unsigned smaskS[8][32];          // this step's spike bits, per b
  __shared__ unsigned stageW[8];              // per-b 32-bit chunk assembly

  const int tid  = threadIdx.x;
  const int mgrp = blockIdx.x & 31;
  const int bgrp = blockIdx.x >> 5;
  const int w    = tid >> 6;
  const int lane = tid & 63;
  const int o    = lane >> 3;
  const int mi   = lane & 7;
  const int mm   = (w << 3) + mi;             // 0..31 local m
  const int m    = (mgrp << 5) + mm;
  const int b    = (bgrp << 3) + o;
  const int col  = (mm + (o << 2)) & 31;      // swizzled Rs column (n>>7 == o)

  // ---- one-time preload of R[:, mgrp*32 .. +32) into LDS (swizzled) ----
  {
    const int mmw = tid & 31;
    const int n0  = tid >> 5;                 // 0..7
    const float* gcol = Rw + (size_t)((mgrp << 5) + mmw);
#pragma unroll 1
    for (int k = 0; k < 128; ++k) {
      const int n = n0 + (k << 3);
      Rs[n * 32 + ((mmw + ((n >> 7) << 2)) & 31)] = gcol[(size_t)n << 10];
    }
  }

  const int b_loc = tid >> 5;                 // 0..7  (spin-read assignment)
  const int ch    = tid & 31;                 // 0..31
  const bool l0 = (o & 1) != 0;
  const bool l1 = ((o >> 1) & 1) != 0;
  const bool l2 = ((o >> 2) & 1) != 0;

  float mem = 0.f, syn = 0.f, spike = 0.f;

  for (int t = 0; t < T_; ++t) {
    const size_t idx = ((size_t)b * T_ + t) * N_ + m;
    const float h = syn_rec[idx];             // early global load (hidden by spin)

    // ---- acquire this step's spike masks (tag == t); t=0 hits memset zeros ----
    {
      unsigned long long* wp =
          masks + (size_t)(t & 1) * (64 * 32) + (size_t)((bgrp << 3) + b_loc) * 32 + ch;
      unsigned long long wv =
          __hip_atomic_load(wp, __ATOMIC_ACQUIRE, __HIP_MEMORY_SCOPE_AGENT);
      int guard = 0;
      while ((unsigned)(wv >> 32) != (unsigned)t && ++guard < (1 << 20)) {
        __builtin_amdgcn_s_sleep(2);
        wv = __hip_atomic_load(wp, __ATOMIC_ACQUIRE, __HIP_MEMORY_SCOPE_AGENT);
      }
      smaskS[b_loc][ch] = (unsigned)wv;
    }
    __syncthreads();                          // barrier #1: smask + Rs(first) ready

    // ---- dense GEMV from LDS: partials for 8 b's over n in [o*128, o*128+128) ----
    float acc[8];
#pragma unroll
    for (int j = 0; j < 8; ++j) acc[j] = 0.f;
    {
      const float* rbase = Rs + (size_t)(o << 7) * 32 + col;
#pragma unroll 1
      for (int c = 0; c < 4; ++c) {
        const unsigned W0 = smaskS[0][(o << 2) + c];
        const unsigned W1 = smaskS[1][(o << 2) + c];
        const unsigned W2 = smaskS[2][(o << 2) + c];
        const unsigned W3 = smaskS[3][(o << 2) + c];
        const unsigned W4 = smaskS[4][(o << 2) + c];
        const unsigned W5 = smaskS[5][(o << 2) + c];
        const unsigned W6 = smaskS[6][(o << 2) + c];
        const unsigned W7 = smaskS[7][(o << 2) + c];
        const float* rc = rbase + (size_t)(c << 5) * 32;
#pragma unroll
        for (int i = 0; i < 32; ++i) {
          const unsigned rv = __float_as_uint(rc[i * 32]);
          acc[0] += __uint_as_float(rv & (unsigned)(((int)(W0 << (31 - i))) >> 31));
          acc[1] += __uint_as_float(rv & (unsigned)(((int)(W1 << (31 - i))) >> 31));
          acc[2] += __uint_as_float(rv & (unsigned)(((int)(W2 << (31 - i))) >> 31));
          acc[3] += __uint_as_float(rv & (unsigned)(((int)(W3 << (31 - i))) >> 31));
          acc[4] += __uint_as_float(rv & (unsigned)(((int)(W4 << (31 - i))) >> 31));
          acc[5] += __uint_as_float(rv & (unsigned)(((int)(W5 << (31 - i))) >> 31));
          acc[6] += __uint_as_float(rv & (unsigned)(((int)(W6 << (31 - i))) >> 31));
          acc[7] += __uint_as_float(rv & (unsigned)(((int)(W7 << (31 - i))) >> 31));
        }
      }
    }

    // ---- 3-stage reduce-scatter across o (xor 8/16/32): lane o keeps j==o ----
    float q0, q1, q2, q3;
    {
      float s, k;
      k = l0 ? acc[1] : acc[0]; s = l0 ? acc[0] : acc[1]; q0 = k + __shfl_xor(s, 8);
      k = l0 ? acc[3] : acc[2]; s = l0 ? acc[2] : acc[3]; q1 = k + __shfl_xor(s, 8);
      k = l0 ? acc[5] : acc[4]; s = l0 ? acc[4] : acc[5]; q2 = k + __shfl_xor(s, 8);
      k = l0 ? acc[7] : acc[6]; s = l0 ? acc[6] : acc[7]; q3 = k + __shfl_xor(s, 8);
    }
    float u0, u1;
    {
      float s, k;
      k = l1 ? q1 : q0; s = l1 ? q0 : q1; u0 = k + __shfl_xor(s, 16);
      k = l1 ? q3 : q2; s = l1 ? q2 : q3; u1 = k + __shfl_xor(s, 16);
    }
    float rec;
    {
      const float s = l2 ? u0 : u1;
      const float k = l2 ? u1 : u0;
      rec = k + __shfl_xor(s, 32);
    }

    // ---- state update for owned (b, m) ----
    syn = ALPHA_ * syn + h + rec;
    mem = BETA_ * mem + syn;
    const float mthr = mem - THR_;
    const bool sp = mthr > 0.f;
    spike = sp ? 1.f : 0.f;
    mem = sp ? 0.f : mem;

    // ---- publish spikes ASAP: tag t+1, slot (t+1)&1 ----
    const unsigned long long ball = __ballot(sp);
    if (mi == 0)
      ((unsigned char*)&stageW[o])[w] = (unsigned char)(ball >> (o << 3));
    __syncthreads();                          // barrier #2: stage ready; GEMV done
    if (tid < 8) {
      const unsigned long long word =
          ((unsigned long long)(unsigned)(t + 1) << 32) | (unsigned long long)stageW[tid];
      unsigned long long* wp =
          masks + (size_t)((t + 1) & 1) * (64 * 32) + (size_t)((bgrp << 3) + tid) * 32 + mgrp;
      __hip_atomic_store(wp, word, __ATOMIC_RELEASE, __HIP_MEMORY_SCOPE_AGENT);
    }

    // ---- stream outputs (fire-and-forget) ----
    spk_rec[idx] = spike;
    mem_rec[idx] = mem;
    syn_rec[idx] = syn;
  }

  const int fi = b * N_ + m;
  mem_fin[fi] = mem;
  syn_fin[fi] = syn;
  spk_fin[fi] = spike;
}

// ============================== launcher =====================================
extern "C" void kernel_launch(void* const* d_in, const int* in_sizes, int n_in,
                              void* d_out, int out_size, void* d_ws, size_t ws_size,
                              hipStream_t stream) {
  const float* X  = (const float*)d_in[0];
  const float* W  = (const float*)d_in[1];
  const float* Rw = (const float*)d_in[2];

  float* out = (float*)d_out;
  const size_t BTN = (size_t)B_ * T_ * N_;
  const size_t BN  = (size_t)B_ * N_;
  float* spk_rec = out;
  float* mem_fin = out + BTN;
  float* syn_fin = mem_fin + BN;
  float* spk_fin = syn_fin + BN;
  float* mem_rec = spk_fin + BN;
  float* syn_rec = mem_rec + BTN;  // doubles as the H buffer

  unsigned long long* masks = (unsigned long long*)d_ws;
  // zero both tag slots (tag 0 == "step 0 ready with no spikes")
  hipMemsetAsync(d_ws, 0, (size_t)2 * 64 * 32 * sizeof(unsigned long long), stream);

  dsrnn_hgemm<<<dim3(1024), dim3(256), 0, stream>>>(X, W, syn_rec);

  (void)hipFuncSetAttribute((const void*)dsrnn_step4,
                            hipFuncAttributeMaxDynamicSharedMemorySize, 131072);
  void* args[] = {(void*)&Rw,      (void*)&spk_rec, (void*)&mem_rec,
                  (void*)&syn_rec, (void*)&mem_fin, (void*)&syn_fin,
                  (void*)&spk_fin, (void*)&masks};
  hipLaunchCooperativeKernel((void*)dsrnn_step4, dim3(256), dim3(256), args,
                             131072, stream);
}

// Round 5
// 3010.144 us; speedup vs baseline: 7.1127x; 1.8626x over previous
//
#include <hip/hip_runtime.h>

static constexpr int   B_  = 64;
static constexpr int   T_  = 256;
static constexpr int   D_  = 512;
static constexpr int   N_  = 1024;
static constexpr float ALPHA_ = 0.9f;
static constexpr float BETA_  = 0.85f;
static constexpr float THR_   = 0.1f;

// ================= Kernel 1: H = X @ W (fp32, 128x128 tiles) =================
__global__ __launch_bounds__(256) void dsrnn_hgemm(const float* __restrict__ X,
                                                   const float* __restrict__ W,
                                                   float* __restrict__ H) {
  __shared__ float As[16][128];
  __shared__ float Bs[16][128];
  const int tid = threadIdx.x;
  const int nb  = blockIdx.x & 7;
  const int mb  = blockIdx.x >> 3;
  const int r0  = mb << 7;
  const int n0  = nb << 7;

  float acc[8][8];
#pragma unroll
  for (int i = 0; i < 8; ++i)
#pragma unroll
    for (int j = 0; j < 8; ++j) acc[i][j] = 0.f;

  for (int k0 = 0; k0 < D_; k0 += 16) {
#pragma unroll
    for (int i = 0; i < 2; ++i) {
      const int f   = tid * 2 + i;
      const int row = f >> 2;
      const int kq  = (f & 3) << 2;
      const float4 v =
          *reinterpret_cast<const float4*>(&X[(size_t)(r0 + row) * D_ + k0 + kq]);
      As[kq + 0][row] = v.x;
      As[kq + 1][row] = v.y;
      As[kq + 2][row] = v.z;
      As[kq + 3][row] = v.w;
    }
#pragma unroll
    for (int i = 0; i < 2; ++i) {
      const int f  = tid * 2 + i;
      const int kr = f >> 5;
      const int c  = (f & 31) << 2;
      *reinterpret_cast<float4*>(&Bs[kr][c]) =
          *reinterpret_cast<const float4*>(&W[(size_t)(k0 + kr) * N_ + n0 + c]);
    }
    __syncthreads();
    const int ty = tid >> 4, tx = tid & 15;
#pragma unroll
    for (int kk = 0; kk < 16; ++kk) {
      float a[8], b[8];
      *reinterpret_cast<float4*>(&a[0]) = *reinterpret_cast<const float4*>(&As[kk][ty * 8]);
      *reinterpret_cast<float4*>(&a[4]) = *reinterpret_cast<const float4*>(&As[kk][ty * 8 + 4]);
      *reinterpret_cast<float4*>(&b[0]) = *reinterpret_cast<const float4*>(&Bs[kk][tx * 8]);
      *reinterpret_cast<float4*>(&b[4]) = *reinterpret_cast<const float4*>(&Bs[kk][tx * 8 + 4]);
#pragma unroll
      for (int i = 0; i < 8; ++i)
#pragma unroll
        for (int j = 0; j < 8; ++j) acc[i][j] = fmaf(a[i], b[j], acc[i][j]);
    }
    __syncthreads();
  }
  const int ty = tid >> 4, tx = tid & 15;
#pragma unroll
  for (int i = 0; i < 8; ++i) {
    const size_t r = (size_t)(r0 + ty * 8 + i);
#pragma unroll
    for (int j = 0; j < 8; j += 4)
      *reinterpret_cast<float4*>(&H[r * N_ + n0 + tx * 8 + j]) =
          *reinterpret_cast<const float4*>(&acc[i][j]);
  }
}

// ====== Kernel 2: persistent recurrence, R in LDS, tagged-dataflow sync ======
// 256 WGs x 256 threads, coop-launched (co-residency) but NO grid.sync and
// NO acquire/release fences: each exchanged word is a self-contained atomic
// u64 = (tag<<32)|bits32; the published value is data-dependent on all
// consumed words (masks -> GEMV -> spikes -> ballot), so RELAXED agent-scope
// atomics suffice for both visibility and overwrite-safety (tag+double buffer).
// WG = (bgrp = bid&7, mgrp = bid>>3): the 32 WGs of a bgrp share an XCD under
// round-robin dispatch (locality heuristic only; correctness placement-free).
__global__ __launch_bounds__(256, 1) void dsrnn_step5(
    const float* __restrict__ Rw,
    float* __restrict__ spk_rec,
    float* __restrict__ mem_rec,
    float* __restrict__ syn_rec,   // pre-filled with H, overwritten with syn
    float* __restrict__ mem_fin,
    float* __restrict__ syn_fin,
    float* __restrict__ spk_fin,
    unsigned long long* masks)
{
  extern __shared__ float Rs[];               // [1024][32] swizzled
  __shared__ unsigned smaskS[8][32];          // this step's spike bits, per b
  __shared__ unsigned stageW[8];              // per-b 32-bit chunk assembly

  const int tid  = threadIdx.x;
  const int bgrp = blockIdx.x & 7;            // same-XCD group (heuristic)
  const int mgrp = blockIdx.x >> 3;
  const int w    = tid >> 6;
  const int lane = tid & 63;
  const int o    = lane >> 3;
  const int mi   = lane & 7;
  const int mm   = (w << 3) + mi;             // 0..31 local m
  const int m    = (mgrp << 5) + mm;
  const int b    = (bgrp << 3) + o;
  const int col  = (mm + (o << 2)) & 31;      // swizzled Rs column (n>>7 == o)

  // ---- one-time preload of R[:, mgrp*32 .. +32) into LDS (swizzled) ----
  {
    const int mmw = tid & 31;
    const int n0  = tid >> 5;                 // 0..7
    const float* gcol = Rw + (size_t)((mgrp << 5) + mmw);
#pragma unroll 1
    for (int k = 0; k < 128; ++k) {
      const int n = n0 + (k << 3);
      Rs[n * 32 + ((mmw + ((n >> 7) << 2)) & 31)] = gcol[(size_t)n << 10];
    }
  }

  const int b_loc = tid >> 5;                 // 0..7  (spin-read assignment)
  const int ch    = tid & 31;                 // 0..31
  const bool l0 = (o & 1) != 0;
  const bool l1 = ((o >> 1) & 1) != 0;
  const bool l2 = ((o >> 2) & 1) != 0;

  float mem = 0.f, syn = 0.f, spike = 0.f;

  for (int t = 0; t < T_; ++t) {
    const size_t idx = ((size_t)b * T_ + t) * N_ + m;
    const float h = syn_rec[idx];             // early global load (hidden by spin)

    // ---- wait for this step's spike masks (tag == t); RELAXED, no fences ----
    {
      unsigned long long* wp =
          masks + (size_t)(t & 1) * (64 * 32) + (size_t)((bgrp << 3) + b_loc) * 32 + ch;
      unsigned long long wv =
          __hip_atomic_load(wp, __ATOMIC_RELAXED, __HIP_MEMORY_SCOPE_AGENT);
      int guard = 0;
      while ((unsigned)(wv >> 32) != (unsigned)t && ++guard < (1 << 20)) {
        __builtin_amdgcn_s_sleep(1);
        wv = __hip_atomic_load(wp, __ATOMIC_RELAXED, __HIP_MEMORY_SCOPE_AGENT);
      }
      smaskS[b_loc][ch] = (unsigned)wv;
    }
    __syncthreads();                          // barrier #1: smask + Rs(first) ready

    // ---- dense GEMV from LDS: partials for 8 b's over n in [o*128, o*128+128) ----
    float acc[8];
#pragma unroll
    for (int j = 0; j < 8; ++j) acc[j] = 0.f;
    {
      const float* rbase = Rs + (size_t)(o << 7) * 32 + col;
#pragma unroll 1
      for (int c = 0; c < 4; ++c) {
        const unsigned W0 = smaskS[0][(o << 2) + c];
        const unsigned W1 = smaskS[1][(o << 2) + c];
        const unsigned W2 = smaskS[2][(o << 2) + c];
        const unsigned W3 = smaskS[3][(o << 2) + c];
        const unsigned W4 = smaskS[4][(o << 2) + c];
        const unsigned W5 = smaskS[5][(o << 2) + c];
        const unsigned W6 = smaskS[6][(o << 2) + c];
        const unsigned W7 = smaskS[7][(o << 2) + c];
        const float* rc = rbase + (size_t)(c << 5) * 32;
#pragma unroll
        for (int i = 0; i < 32; ++i) {
          const unsigned rv = __float_as_uint(rc[i * 32]);
          acc[0] += __uint_as_float(rv & (unsigned)(((int)(W0 << (31 - i))) >> 31));
          acc[1] += __uint_as_float(rv & (unsigned)(((int)(W1 << (31 - i))) >> 31));
          acc[2] += __uint_as_float(rv & (unsigned)(((int)(W2 << (31 - i))) >> 31));
          acc[3] += __uint_as_float(rv & (unsigned)(((int)(W3 << (31 - i))) >> 31));
          acc[4] += __uint_as_float(rv & (unsigned)(((int)(W4 << (31 - i))) >> 31));
          acc[5] += __uint_as_float(rv & (unsigned)(((int)(W5 << (31 - i))) >> 31));
          acc[6] += __uint_as_float(rv & (unsigned)(((int)(W6 << (31 - i))) >> 31));
          acc[7] += __uint_as_float(rv & (unsigned)(((int)(W7 << (31 - i))) >> 31));
        }
      }
    }

    // ---- 3-stage reduce-scatter across o (xor 8/16/32): lane o keeps j==o ----
    float q0, q1, q2, q3;
    {
      float s, k;
      k = l0 ? acc[1] : acc[0]; s = l0 ? acc[0] : acc[1]; q0 = k + __shfl_xor(s, 8);
      k = l0 ? acc[3] : acc[2]; s = l0 ? acc[2] : acc[3]; q1 = k + __shfl_xor(s, 8);
      k = l0 ? acc[5] : acc[4]; s = l0 ? acc[4] : acc[5]; q2 = k + __shfl_xor(s, 8);
      k = l0 ? acc[7] : acc[6]; s = l0 ? acc[6] : acc[7]; q3 = k + __shfl_xor(s, 8);
    }
    float u0, u1;
    {
      float s, k;
      k = l1 ? q1 : q0; s = l1 ? q0 : q1; u0 = k + __shfl_xor(s, 16);
      k = l1 ? q3 : q2; s = l1 ? q2 : q3; u1 = k + __shfl_xor(s, 16);
    }
    float rec;
    {
      const float s = l2 ? u0 : u1;
      const float k = l2 ? u1 : u0;
      rec = k + __shfl_xor(s, 32);
    }

    // ---- state update for owned (b, m) ----
    syn = ALPHA_ * syn + h + rec;
    mem = BETA_ * mem + syn;
    const float mthr = mem - THR_;
    const bool sp = mthr > 0.f;
    spike = sp ? 1.f : 0.f;
    mem = sp ? 0.f : mem;

    // ---- publish spikes ASAP: tag t+1, slot (t+1)&1 (RELAXED, data-dep safe) ----
    const unsigned long long ball = __ballot(sp);
    if (mi == 0)
      ((unsigned char*)&stageW[o])[w] = (unsigned char)(ball >> (o << 3));
    __syncthreads();                          // barrier #2: stage ready; GEMV done
    if (tid < 8) {
      const unsigned long long word =
          ((unsigned long long)(unsigned)(t + 1) << 32) | (unsigned long long)stageW[tid];
      unsigned long long* wp =
          masks + (size_t)((t + 1) & 1) * (64 * 32) + (size_t)((bgrp << 3) + tid) * 32 + mgrp;
      __hip_atomic_store(wp, word, __ATOMIC_RELAXED, __HIP_MEMORY_SCOPE_AGENT);
    }

    // ---- stream outputs (fire-and-forget) ----
    spk_rec[idx] = spike;
    mem_rec[idx] = mem;
    syn_rec[idx] = syn;
  }

  const int fi = b * N_ + m;
  mem_fin[fi] = mem;
  syn_fin[fi] = syn;
  spk_fin[fi] = spike;
}

// ============================== launcher =====================================
extern "C" void kernel_launch(void* const* d_in, const int* in_sizes, int n_in,
                              void* d_out, int out_size, void* d_ws, size_t ws_size,
                              hipStream_t stream) {
  const float* X  = (const float*)d_in[0];
  const float* W  = (const float*)d_in[1];
  const float* Rw = (const float*)d_in[2];

  float* out = (float*)d_out;
  const size_t BTN = (size_t)B_ * T_ * N_;
  const size_t BN  = (size_t)B_ * N_;
  float* spk_rec = out;
  float* mem_fin = out + BTN;
  float* syn_fin = mem_fin + BN;
  float* spk_fin = syn_fin + BN;
  float* mem_rec = spk_fin + BN;
  float* syn_rec = mem_rec + BTN;  // doubles as the H buffer

  unsigned long long* masks = (unsigned long long*)d_ws;
  // zero both tag slots (tag 0 == "step 0 ready with no spikes")
  hipMemsetAsync(d_ws, 0, (size_t)2 * 64 * 32 * sizeof(unsigned long long), stream);

  dsrnn_hgemm<<<dim3(1024), dim3(256), 0, stream>>>(X, W, syn_rec);

  (void)hipFuncSetAttribute((const void*)dsrnn_step5,
                            hipFuncAttributeMaxDynamicSharedMemorySize, 131072);
  void* args[] = {(void*)&Rw,      (void*)&spk_rec, (void*)&mem_rec,
                  (void*)&syn_rec, (void*)&mem_fin, (void*)&syn_fin,
                  (void*)&spk_fin, (void*)&masks};
  hipLaunchCooperativeKernel((void*)dsrnn_step5, dim3(256), dim3(256), args,
                             131072, stream);
}

// Round 7
// 887.400 us; speedup vs baseline: 24.1269x; 3.3921x over previous
//
#include <hip/hip_runtime.h>

typedef __attribute__((ext_vector_type(8))) _Float16 f16x8;
typedef __attribute__((ext_vector_type(4))) float f32x4;

static constexpr int   B_  = 64;
static constexpr int   T_  = 256;
static constexpr int   D_  = 512;
static constexpr int   N_  = 1024;
static constexpr float ALPHA_ = 0.9f;
static constexpr float BETA_  = 0.85f;
static constexpr float THR_   = 0.1f;

// ================= Kernel 1: H = X @ W (fp32, 128x128 tiles) =================
__global__ __launch_bounds__(256) void dsrnn_hgemm(const float* __restrict__ X,
                                                   const float* __restrict__ W,
                                                   float* __restrict__ H) {
  __shared__ float As[16][128];
  __shared__ float Bs[16][128];
  const int tid = threadIdx.x;
  const int nb  = blockIdx.x & 7;
  const int mb  = blockIdx.x >> 3;
  const int r0  = mb << 7;
  const int n0  = nb << 7;

  float acc[8][8];
#pragma unroll
  for (int i = 0; i < 8; ++i)
#pragma unroll
    for (int j = 0; j < 8; ++j) acc[i][j] = 0.f;

  for (int k0 = 0; k0 < D_; k0 += 16) {
#pragma unroll
    for (int i = 0; i < 2; ++i) {
      const int f   = tid * 2 + i;
      const int row = f >> 2;
      const int kq  = (f & 3) << 2;
      const float4 v =
          *reinterpret_cast<const float4*>(&X[(size_t)(r0 + row) * D_ + k0 + kq]);
      As[kq + 0][row] = v.x;
      As[kq + 1][row] = v.y;
      As[kq + 2][row] = v.z;
      As[kq + 3][row] = v.w;
    }
#pragma unroll
    for (int i = 0; i < 2; ++i) {
      const int f  = tid * 2 + i;
      const int kr = f >> 5;
      const int c  = (f & 31) << 2;
      *reinterpret_cast<float4*>(&Bs[kr][c]) =
          *reinterpret_cast<const float4*>(&W[(size_t)(k0 + kr) * N_ + n0 + c]);
    }
    __syncthreads();
    const int ty = tid >> 4, tx = tid & 15;
#pragma unroll
    for (int kk = 0; kk < 16; ++kk) {
      float a[8], b[8];
      *reinterpret_cast<float4*>(&a[0]) = *reinterpret_cast<const float4*>(&As[kk][ty * 8]);
      *reinterpret_cast<float4*>(&a[4]) = *reinterpret_cast<const float4*>(&As[kk][ty * 8 + 4]);
      *reinterpret_cast<float4*>(&b[0]) = *reinterpret_cast<const float4*>(&Bs[kk][tx * 8]);
      *reinterpret_cast<float4*>(&b[4]) = *reinterpret_cast<const float4*>(&Bs[kk][tx * 8 + 4]);
#pragma unroll
      for (int i = 0; i < 8; ++i)
#pragma unroll
        for (int j = 0; j < 8; ++j) acc[i][j] = fmaf(a[i], b[j], acc[i][j]);
    }
    __syncthreads();
  }
  const int ty = tid >> 4, tx = tid & 15;
#pragma unroll
  for (int i = 0; i < 8; ++i) {
    const size_t r = (size_t)(r0 + ty * 8 + i);
#pragma unroll
    for (int j = 0; j < 8; j += 4)
      *reinterpret_cast<float4*>(&H[r * N_ + n0 + tx * 8 + j]) =
          *reinterpret_cast<const float4*>(&acc[i][j]);
  }
}

// ====== Kernel 2: persistent recurrence via MFMA (fp16 hi + scaled-lo) =======
// 128 WGs x 256 threads, coop-launched, tagged-dataflow sync (relaxed agent
// atomics; tag+payload in one u64, data-dependence makes it safe).
// WG = (bq = bid>>5 in 0..3, mg = bid&31 in 0..31): owns 16 b's x 32 m's.
// R = hi + lo/4096 with hi = fp16(v), lo = fp16((v-hi)*4096): residual
// ~2^-24*|v| (below fp32-sum rounding); spike(0/1) products exact.
// LDS RsB (128 KB): blocks [32 s][mt0_hi|mt0_lo|mt1_hi|mt1_lo][64 lane][16B];
//   element R[k = s*32 + (lane>>4)*8 + j][m = mg*32 + mt*16 + (lane&15)].
// A-frag (spikes): row = b-local = lane&15, same k-slot map as B -> contraction
// robust to any k permutation. C layout (HW-verified): col=lane&15,
// row=(lane>>4)*4+reg. hi/lo go to SEPARATE fp32 accumulators, combined
// c_hi + c_lo/4096 at scratch-write. Wave wv covers K-steps [wv*8, wv*8+8).
__global__ __launch_bounds__(256, 1) void dsrnn_step7(
    const float* __restrict__ Rw,
    float* __restrict__ spk_rec,
    float* __restrict__ mem_rec,
    float* __restrict__ syn_rec,   // pre-filled with H, overwritten with syn
    float* __restrict__ mem_fin,
    float* __restrict__ syn_fin,
    float* __restrict__ spk_fin,
    unsigned long long* masks)
{
  extern __shared__ unsigned char RsB[];   // 128 KB fragment blocks
  __shared__ unsigned smaskU[16][33];      // padded
  __shared__ float scratch[4][512];        // per-wave C partials [wv][b*32+m]

  const int tid  = threadIdx.x;
  const int bq   = blockIdx.x >> 5;
  const int mg   = blockIdx.x & 31;
  const int wv   = tid >> 6;
  const int lane = tid & 63;
  const int kg   = lane >> 4;
  const int cc   = lane & 15;

  // ---- one-time preload: R[:, mg*32..+32) -> fp16 hi / scaled-lo blocks ----
  for (int k = 0; k < 128; ++k) {
    const int e  = (k << 8) + tid;
    const int n  = e >> 5;
    const int ml = e & 31;
    const float v = Rw[(size_t)n * N_ + (mg << 5) + ml];
    const _Float16 hi = (_Float16)v;
    const float hif = (float)hi;
    const _Float16 lo = (_Float16)((v - hif) * 4096.0f);
    const int s   = n >> 5;
    const int kin = n & 31;
    const int ln  = ((kin >> 3) << 4) + (ml & 15);
    const int mt  = ml >> 4;
    const int off = ((((s << 1) + mt) << 1) << 10) + (ln << 4) + ((kin & 7) << 1);
    *(_Float16*)(RsB + off)        = hi;
    *(_Float16*)(RsB + off + 1024) = lo;
  }

  const int bl1 = tid >> 5;                // 0..7
  const int bl2 = bl1 + 8;
  const int ml_ = tid & 31;
  const int b1  = (bq << 4) + bl1;
  const int b2  = (bq << 4) + bl2;
  const int m   = (mg << 5) + ml_;

  float mem1 = 0.f, syn1 = 0.f, spv1 = 0.f;
  float mem2 = 0.f, syn2 = 0.f, spv2 = 0.f;

  __syncthreads();                         // preload visible to all

  for (int t = 0; t < T_; ++t) {
    const size_t i1 = ((size_t)b1 * T_ + t) * N_ + m;
    const size_t i2 = ((size_t)b2 * T_ + t) * N_ + m;
    const float h1 = syn_rec[i1];          // issue early, consumed post-GEMM
    const float h2 = syn_rec[i2];

    // ---- spin for the two owned mask words (tag == t); relaxed agent ----
    {
      unsigned long long* base = masks + (size_t)(t & 1) * 2048;
      unsigned long long* p1 = base + (size_t)b1 * 32 + ml_;
      unsigned long long* p2 = base + (size_t)b2 * 32 + ml_;
      unsigned long long w1 =
          __hip_atomic_load(p1, __ATOMIC_RELAXED, __HIP_MEMORY_SCOPE_AGENT);
      int g = 0;
      while ((unsigned)(w1 >> 32) != (unsigned)t && ++g < (1 << 20)) {
        __builtin_amdgcn_s_sleep(1);
        w1 = __hip_atomic_load(p1, __ATOMIC_RELAXED, __HIP_MEMORY_SCOPE_AGENT);
      }
      unsigned long long w2 =
          __hip_atomic_load(p2, __ATOMIC_RELAXED, __HIP_MEMORY_SCOPE_AGENT);
      g = 0;
      while ((unsigned)(w2 >> 32) != (unsigned)t && ++g < (1 << 20)) {
        __builtin_amdgcn_s_sleep(1);
        w2 = __hip_atomic_load(p2, __ATOMIC_RELAXED, __HIP_MEMORY_SCOPE_AGENT);
      }
      smaskU[bl1][ml_] = (unsigned)w1;
      smaskU[bl2][ml_] = (unsigned)w2;
    }
    __syncthreads();                       // #1: masks staged

    // ---- MFMA phase: wave's 8 K-steps; hi and lo into separate fp32 C ----
    f32x4 c0h = {0.f, 0.f, 0.f, 0.f};
    f32x4 c0l = {0.f, 0.f, 0.f, 0.f};
    f32x4 c1h = {0.f, 0.f, 0.f, 0.f};
    f32x4 c1l = {0.f, 0.f, 0.f, 0.f};
    const int shB = kg << 3;
#pragma unroll
    for (int ss = 0; ss < 8; ++ss) {
      const int s = (wv << 3) + ss;
      const unsigned bits8 = (smaskU[cc][s] >> shB) & 0xFFu;
      union { unsigned u[4]; f16x8 v; } A;
#pragma unroll
      for (int p = 0; p < 4; ++p) {
        const unsigned e0 = (bits8 >> (2 * p)) & 1u;
        const unsigned e1 = (bits8 >> (2 * p + 1)) & 1u;
        A.u[p] = e0 * 0x3C00u + e1 * 0x3C000000u;   // fp16 1.0 per slot
      }
      const unsigned char* sb = RsB + (s << 12) + (lane << 4);
      const f16x8 b00 = *reinterpret_cast<const f16x8*>(sb);          // mt0 hi
      const f16x8 b01 = *reinterpret_cast<const f16x8*>(sb + 1024);   // mt0 lo
      const f16x8 b10 = *reinterpret_cast<const f16x8*>(sb + 2048);   // mt1 hi
      const f16x8 b11 = *reinterpret_cast<const f16x8*>(sb + 3072);   // mt1 lo
      c0h = __builtin_amdgcn_mfma_f32_16x16x32_f16(A.v, b00, c0h, 0, 0, 0);
      c0l = __builtin_amdgcn_mfma_f32_16x16x32_f16(A.v, b01, c0l, 0, 0, 0);
      c1h = __builtin_amdgcn_mfma_f32_16x16x32_f16(A.v, b10, c1h, 0, 0, 0);
      c1l = __builtin_amdgcn_mfma_f32_16x16x32_f16(A.v, b11, c1l, 0, 0, 0);
    }
    constexpr float INV4096 = 1.0f / 4096.0f;
#pragma unroll
    for (int r = 0; r < 4; ++r) {
      const int row = (kg << 2) + r;
      scratch[wv][(row << 5) + cc]      = fmaf(c0l[r], INV4096, c0h[r]);
      scratch[wv][(row << 5) + cc + 16] = fmaf(c1l[r], INV4096, c1h[r]);
    }
    __syncthreads();                       // #2: partials ready

    // ---- K-reduce + state update for the 2 owned (b, m) ----
    const int o1 = (bl1 << 5) + ml_;
    const int o2 = (bl2 << 5) + ml_;
    const float rec1 =
        scratch[0][o1] + scratch[1][o1] + scratch[2][o1] + scratch[3][o1];
    const float rec2 =
        scratch[0][o2] + scratch[1][o2] + scratch[2][o2] + scratch[3][o2];

    syn1 = ALPHA_ * syn1 + h1 + rec1;
    mem1 = BETA_ * mem1 + syn1;
    const bool sp1 = (mem1 - THR_) > 0.f;
    spv1 = sp1 ? 1.f : 0.f;
    mem1 = sp1 ? 0.f : mem1;

    syn2 = ALPHA_ * syn2 + h2 + rec2;
    mem2 = BETA_ * mem2 + syn2;
    const bool sp2 = (mem2 - THR_) > 0.f;
    spv2 = sp2 ? 1.f : 0.f;
    mem2 = sp2 ? 0.f : mem2;

    // ---- publish spikes (tag t+1) before the bulk stores ----
    const unsigned long long ball1 = __ballot(sp1);
    const unsigned long long ball2 = __ballot(sp2);
    if (ml_ == 0) {                        // lanes 0 and 32 of each wave
      const unsigned sh = lane & 32;
      const unsigned long long tag = ((unsigned long long)(unsigned)(t + 1)) << 32;
      unsigned long long* nb = masks + (size_t)((t + 1) & 1) * 2048;
      __hip_atomic_store(nb + (size_t)b1 * 32 + mg,
                         tag | (unsigned)(ball1 >> sh),
                         __ATOMIC_RELAXED, __HIP_MEMORY_SCOPE_AGENT);
      __hip_atomic_store(nb + (size_t)b2 * 32 + mg,
                         tag | (unsigned)(ball2 >> sh),
                         __ATOMIC_RELAXED, __HIP_MEMORY_SCOPE_AGENT);
    }

    // ---- stream outputs ----
    spk_rec[i1] = spv1; mem_rec[i1] = mem1; syn_rec[i1] = syn1;
    spk_rec[i2] = spv2; mem_rec[i2] = mem2; syn_rec[i2] = syn2;
  }

  mem_fin[b1 * N_ + m] = mem1; syn_fin[b1 * N_ + m] = syn1; spk_fin[b1 * N_ + m] = spv1;
  mem_fin[b2 * N_ + m] = mem2; syn_fin[b2 * N_ + m] = syn2; spk_fin[b2 * N_ + m] = spv2;
}

// ============================== launcher =====================================
extern "C" void kernel_launch(void* const* d_in, const int* in_sizes, int n_in,
                              void* d_out, int out_size, void* d_ws, size_t ws_size,
                              hipStream_t stream) {
  const float* X  = (const float*)d_in[0];
  const float* W  = (const float*)d_in[1];
  const float* Rw = (const float*)d_in[2];

  float* out = (float*)d_out;
  const size_t BTN = (size_t)B_ * T_ * N_;
  const size_t BN  = (size_t)B_ * N_;
  float* spk_rec = out;
  float* mem_fin = out + BTN;
  float* syn_fin = mem_fin + BN;
  float* spk_fin = syn_fin + BN;
  float* mem_rec = spk_fin + BN;
  float* syn_rec = mem_rec + BTN;  // doubles as the H buffer

  unsigned long long* masks = (unsigned long long*)d_ws;
  // zero both tag slots (tag 0 == "step 0 ready with no spikes")
  hipMemsetAsync(d_ws, 0, (size_t)2 * 64 * 32 * sizeof(unsigned long long), stream);

  dsrnn_hgemm<<<dim3(1024), dim3(256), 0, stream>>>(X, W, syn_rec);

  (void)hipFuncSetAttribute((const void*)dsrnn_step7,
                            hipFuncAttributeMaxDynamicSharedMemorySize, 131072);
  void* args[] = {(void*)&Rw,      (void*)&spk_rec, (void*)&mem_rec,
                  (void*)&syn_rec, (void*)&mem_fin, (void*)&syn_fin,
                  (void*)&spk_fin, (void*)&masks};
  hipLaunchCooperativeKernel((void*)dsrnn_step7, dim3(128), dim3(256), args,
                             131072, stream);
}